// Round 3
// baseline (676.202 us; speedup 1.0000x reference)
//
#include <hip/hip_runtime.h>
#include <hip/hip_bf16.h>

#define MT 32768      // tokens total (64*512)
#define KD 2048       // B*C = 32*64
#define DD 256        // embedding dim
#define NB 32         // codebooks
#define NC 64         // codewords
#define LOG2E 1.44269504f

typedef short s8v __attribute__((ext_vector_type(8)));   // 8 x bf16 (4 VGPRs)
typedef float f4v __attribute__((ext_vector_type(4)));   // MFMA accumulator
typedef unsigned short u16;
typedef unsigned int u32;

__device__ __forceinline__ u16 f2bf(float x) {
  u32 u = __float_as_uint(x);
  u += 0x7FFFu + ((u >> 16) & 1u);
  return (u16)(u >> 16);
}

// ---------------- pack_b: codebook (32,64,256) f32 -> Bp MFMA-B-fragment order (1 MiB)
// Frag (nt, s, lane): value[j] = B[k = s*32 + (lane>>4)*8 + j][n = nt*16 + (lane&15)]
__global__ void pack_b(const float* __restrict__ cb, u16* __restrict__ Bp) {
  int idx = blockIdx.x * 256 + threadIdx.x;   // 0..65535 fragments
  int lane = idx & 63;
  int s = (idx >> 6) & 63;
  int nt = idx >> 12;
  int n = nt * 16 + (lane & 15);
  int kb = s * 32 + (lane >> 4) * 8;
  s8v v;
#pragma unroll
  for (int j = 0; j < 8; ++j) v[j] = (short)f2bf(cb[(size_t)(kb + j) * DD + n]);
  *(s8v*)(Bp + (size_t)idx * 8) = v;
}

// ---------------- K1: gather + single-pass softmax -> Wf (A-fragment order, 128 MiB bf16)
// Wf frag index f = (mtile*64 + s)*64 + (q*16 + lid); element j; k = 32s+8q+j, m = 16*mtile+lid.
// Token value (b, c=lane): k = b*64+lane -> s = 2b+(lane>>5), q=(lane>>3)&3, j=lane&7.
// Per lane, q/j/(lane>>5) are fixed; stores stride b*1024 u16 (2 KB).
__global__ __launch_bounds__(256, 4) void build_w(
    const int* __restrict__ tokens, const float* __restrict__ code,
    u16* __restrict__ Wf) {
  const int t = threadIdx.x;
  const int w = t >> 6, lane = t & 63;
  const int mtile = blockIdx.x;         // 0..2047, 16 tokens each
  const int q = (lane >> 3) & 3, j = lane & 7, shi = lane >> 5;

#pragma unroll 1
  for (int i = 0; i < 4; ++i) {
    const int m_local = w * 4 + i;      // = lid
    const int m = mtile * 16 + m_local;
    const int tok = tokens[m];
    const float* row = code + (size_t)tok * KD + lane;
    float g[NB];
#pragma unroll
    for (int b = 0; b < NB; ++b) g[b] = row[b * NC];   // 32 coalesced 256B loads, single pass
    float mx = g[0];
#pragma unroll
    for (int b = 1; b < NB; ++b) mx = fmaxf(mx, g[b]);
    float s = 0.f;
#pragma unroll
    for (int b = 0; b < NB; ++b) {
      g[b] = exp2f((g[b] - mx) * LOG2E);
      s += g[b];
    }
    const float inv = 1.0f / s;
    u16* base = Wf + ((((size_t)mtile * 64 + shi) * 64) + q * 16 + m_local) * 8 + j;
#pragma unroll
    for (int b = 0; b < NB; ++b) base[b * 1024] = f2bf(g[b] * inv);
  }
}

// ---------------- K2: GEMM  M=32768 x K=2048 x N=256, A from Wf (frag order, HBM via
// global_load_lds 16B), B from Bp (L2-hot, direct with 1-deep prefetch).
// Block: 256 thr (4 waves), Mblock=32 (2 mtiles), wave = one 64-wide N-group. Grid 1024.
#define CSTEP 16   // k-steps per staged chunk (4 chunks of 16 -> K=2048)
__global__ __launch_bounds__(256, 4) void gemm_w(
    const u16* __restrict__ Wf, const u16* __restrict__ Bp, float* __restrict__ out) {
  __shared__ __align__(16) u16 A[2 * CSTEP * 64 * 8];   // 32 KB: [mt][sl][lane][8]

  const int t = threadIdx.x;
  const int w = t >> 6, lane = t & 63;
  const int mb = blockIdx.x;            // 0..1023
  const int lid = lane & 15, quad = lane >> 4;
  const int ng = w;

  const u16* wfb = Wf + (size_t)mb * 2 * 64 * 64 * 8;   // 2 mtiles x 64 KB

  auto ldB = [&](int nt, int s) -> s8v {
    const int fi = ((ng * 4 + nt) * 64 + s) * 64 + lane;
    return *(const s8v*)(Bp + (size_t)fi * 8);
  };

  f4v acc[2][4] = {};
  s8v bc[4], bn[4];
#pragma unroll
  for (int nt = 0; nt < 4; ++nt) bc[nt] = ldB(nt, 0);

  for (int ch = 0; ch < 4; ++ch) {
    // ---- stage A chunk: 2 mtiles x 16 steps x 1 KB = 32 KB, async 16B copies
#pragma unroll
    for (int r = 0; r < 8; ++r) {
      const int flat = r * 256 + t;           // [mt(1b)][sl(4b)][lane(6b)]
      const int mt = flat >> 10;
      const int rem = flat & 1023;            // sl*64 + lane
      const u16* gp = wfb + ((size_t)mt * 64 * 64 + (size_t)ch * CSTEP * 64 + rem) * 8;
      u16* lp = A + (size_t)flat * 8;
      __builtin_amdgcn_global_load_lds(
          (const __attribute__((address_space(1))) u32*)gp,
          (__attribute__((address_space(3))) u32*)lp, 16, 0, 0);
    }
    __syncthreads();   // drains vmcnt: A chunk resident (bc regs already hold values)

    // ---- compute 16 k-steps
#pragma unroll 1
    for (int sl = 0; sl < CSTEP; ++sl) {
      const int s = ch * CSTEP + sl;
      const int sn = (s + 1 < 64) ? s + 1 : 63;
#pragma unroll
      for (int nt = 0; nt < 4; ++nt) bn[nt] = ldB(nt, sn);   // prefetch next-step B
      s8v a0 = *(const s8v*)(A + ((0 * CSTEP + sl) * 64 + lane) * 8);
      s8v a1 = *(const s8v*)(A + ((1 * CSTEP + sl) * 64 + lane) * 8);
#pragma unroll
      for (int nt = 0; nt < 4; ++nt) {
        acc[0][nt] = __builtin_amdgcn_mfma_f32_16x16x32_bf16(a0, bc[nt], acc[0][nt], 0, 0, 0);
        acc[1][nt] = __builtin_amdgcn_mfma_f32_16x16x32_bf16(a1, bc[nt], acc[1][nt], 0, 0, 0);
      }
#pragma unroll
      for (int nt = 0; nt < 4; ++nt) bc[nt] = bn[nt];
    }
    __syncthreads();   // protect A before next chunk's staging overwrites
  }

  // ---- epilogue: C/D layout col = lane&15, row = quad*4 + reg  [m89/m91]
  float* ob = out + (size_t)(mb * 32) * DD + ng * 64 + lid;
#pragma unroll
  for (int mt = 0; mt < 2; ++mt)
#pragma unroll
    for (int r = 0; r < 4; ++r) {
      float* p = ob + (size_t)(mt * 16 + quad * 4 + r) * DD;
#pragma unroll
      for (int nt = 0; nt < 4; ++nt) p[nt * 16] = acc[mt][nt][r];
    }
}

extern "C" void kernel_launch(void* const* d_in, const int* in_sizes, int n_in,
                              void* d_out, int out_size, void* d_ws, size_t ws_size,
                              hipStream_t stream) {
  const int* tokens = (const int*)d_in[0];
  const float* code = (const float*)d_in[1];
  const float* codebook = (const float*)d_in[2];
  float* out = (float*)d_out;

  u16* Bp = (u16*)d_ws;                         // 1 MiB B fragments
  u16* Wf = (u16*)d_ws + (1u << 19);            // +1 MiB: 128 MiB A fragments

  pack_b<<<256, 256, 0, stream>>>(codebook, Bp);
  build_w<<<MT / 16, 256, 0, stream>>>(tokens, code, Wf);
  gemm_w<<<MT / 32, 256, 0, stream>>>(Wf, Bp, out);
}